// Round 11
// baseline (209.986 us; speedup 1.0000x reference)
//
#include <hip/hip_runtime.h>
#include <hip/hip_cooperative_groups.h>
#include <math.h>

namespace cg = cooperative_groups;
typedef unsigned long long ull;

// Problem constants (from setup_inputs): B=64, G=4999, P=50
constexpr int Bc = 64;
constexpr int Gc = 4999;
constexpr int Pc = 50;

constexpr int RUN   = 1024;          // elements per sorted run
constexpr int NRUN  = 5;             // runs per row (5*1024 = 5120 >= G)
constexpr int NPAD  = NRUN * RUN;
constexpr int LPW   = 79;            // genes per lane in es phase
constexpr ull PADKEY = 0xFFFFFFFFFFFFFFFFull;

__device__ __forceinline__ ull shfl_xor64(ull v, int lm) {
    int lo = __shfl_xor((int)(unsigned)(v & 0xFFFFFFFFull), lm, 64);
    int hi = __shfl_xor((int)(unsigned)(v >> 32), lm, 64);
    return ((ull)(unsigned)hi << 32) | (unsigned)lo;
}

// ---------------------------------------------------------------------------
// ONE cooperative kernel, grid (5,64) x 256 threads (320 blocks, all
// co-resident: 40 KB LDS -> 4 blocks/CU capacity = 1024 >= 320).
//   phase 1: block (rg,b) bitonic-sorts run rg of sample b (round-10 verified
//            network; r==0 blocks also pack pbits) -> global runs[]
//   grid.sync()
//   phase 2: block (rg,b) stages all 5 runs of b (40 KB LDS) and ranks
//            elements [rg*1024, rg*1024+1024), 4/thread: rank = own-run pos +
//            4 binary searches (exact bijection, keys unique) -> wq[] + sidx[]
//   grid.sync()
//   phase 3: block remapped to (pg,b): pathways [pg*10, pg*10+10); stages
//            swq + sm32 = (u32)(pbits[sidx[i]] >> pg*10); wave w scans
//            {3,3,2,2} pathways over its 79-gene chunk (verified scan math).
// ---------------------------------------------------------------------------
__global__ __launch_bounds__(256) void fused_all(
    const float* __restrict__ expr, const float* __restrict__ pathway,
    ull* __restrict__ pbits, ull* __restrict__ runs,
    float* __restrict__ wq, unsigned short* __restrict__ sidx,
    float* __restrict__ out)
{
    __shared__ union {
        ull key[RUN];                                  //  8192 B (phase 1)
        ull runsLDS[NPAD];                             // 40960 B (phase 2)
        struct { float swq[Gc]; unsigned sm32[Gc]; } es;  // ~40 KB (phase 3)
    } lds;

    const int rg = blockIdx.x, b = blockIdx.y, tid = threadIdx.x;
    const int G = Gc, P = Pc;
    cg::grid_group grid = cg::this_grid();

    // ================= Phase 1: sort run rg of sample b =================
    {
        const int base = tid * 4;
        const float* row = expr + (size_t)b * G;
        ull v[4];
#pragma unroll
        for (int o = 0; o < 4; ++o) {
            int i = rg * RUN + base + o;
            if (i < G) {
                unsigned u = __float_as_uint(row[i]);
                unsigned m = (u >> 31) ? ~u : (u | 0x80000000u);  // monotone
                v[o] = ((ull)(~m) << 32) | (unsigned)i;
            } else {
                v[o] = PADKEY;
            }
        }

        for (int kk = 2; kk <= RUN; kk <<= 1) {
            const int j0 = kk >> 1;
            if (j0 >= 256) {            // LDS stages (cross-wave)
#pragma unroll
                for (int o = 0; o < 4; ++o) lds.key[base + o] = v[o];
                __syncthreads();
                for (int j = j0; j >= 256; j >>= 1) {
#pragma unroll
                    for (int t = tid; t < RUN / 2; t += 256) {
                        int i  = ((t & ~(j - 1)) << 1) | (t & (j - 1));
                        int ix = i | j;
                        ull a = lds.key[i], c = lds.key[ix];
                        bool up = ((i & kk) == 0);
                        if ((a > c) == up) { lds.key[i] = c; lds.key[ix] = a; }
                    }
                    __syncthreads();
                }
#pragma unroll
                for (int o = 0; o < 4; ++o) v[o] = lds.key[base + o];
            }
            int jstart = (j0 > 128) ? 128 : j0;   // wave-shuffle stages
            for (int j = jstart; j >= 4; j >>= 1) {
                int lm = j >> 2;
                bool takeMin = (((tid & lm) == 0) == ((base & kk) == 0));
#pragma unroll
                for (int o = 0; o < 4; ++o) {
                    ull c = shfl_xor64(v[o], lm);
                    ull mn = (v[o] < c) ? v[o] : c;
                    ull mx = (v[o] < c) ? c : v[o];
                    v[o] = takeMin ? mn : mx;
                }
            }
#pragma unroll
            for (int j = 2; j >= 1; j >>= 1) {    // register stages
                if (j < kk) {
#pragma unroll
                    for (int o = 0; o < 4; ++o) {
                        if ((o & j) == 0) {
                            bool up = (((base + o) & kk) == 0);
                            ull a = v[o], c = v[o | j];
                            if ((a > c) == up) { v[o] = c; v[o | j] = a; }
                        }
                    }
                }
            }
        }

        ull* dst = runs + ((size_t)b * NRUN + rg) * RUN;
#pragma unroll
        for (int o = 0; o < 4; ++o) dst[base + o] = v[o];

        // Folded pack: blocks with rg==0 (64 x 256 = 16384 >= G).
        if (rg == 0) {
            int g = b * 256 + tid;
            if (g < G) {
                ull m = 0;
#pragma unroll
                for (int p = 0; p < Pc; ++p)
                    if (pathway[(size_t)p * G + g] > 0.0f) m |= (1ull << p);
                pbits[g] = m;
            }
        }
    }

    grid.sync();
    __syncthreads();   // ensure LDS reuse is safe within the block

    // ================= Phase 2: rank 4 elements per thread =================
    {
        const ull* rowruns = runs + (size_t)b * NPAD;
        for (int i = tid; i < NPAD; i += 256) lds.runsLDS[i] = rowruns[i];
        __syncthreads();

#pragma unroll
        for (int o = 0; o < 4; ++o) {
            const int e = rg * 1024 + o * 256 + tid;   // 0..5119
            const ull keyv = lds.runsLDS[e];
            if (keyv == PADKEY) continue;              // padding
            const int run = e >> 10;
            int rank = e & 1023;                       // own-run pos (stable)
#pragma unroll
            for (int rr = 0; rr < NRUN; ++rr) {
                if (rr == run) continue;
                const ull* arr = &lds.runsLDS[rr * RUN];
                int pos = 0;
#pragma unroll
                for (int s = RUN; s >= 1; s >>= 1) {
                    int np = pos + s;
                    if (np <= RUN && arr[np - 1] < keyv) pos = np;
                }
                rank += pos;                           // # elements < keyv
            }
            int idx = (int)(unsigned)(keyv & 0xFFFFFFFFu);
            unsigned m = ~((unsigned)(keyv >> 32));
            unsigned absbits = ((m >> 31) ? m : ~m) & 0x7FFFFFFFu;
            float av = __uint_as_float(absbits);
            wq[(size_t)b * G + rank] = sqrtf(sqrtf(av));     // |v|^0.25
            sidx[(size_t)b * G + rank] = (unsigned short)idx;
        }
    }

    grid.sync();
    __syncthreads();

    // ================= Phase 3: es, 10 pathways per block =================
    {
        const int pg = rg;                 // reuse block coords: (pg, b)
        const int pbeg = pg * 10;

        for (int i = tid; i < G; i += 256) {
            lds.es.swq[i]  = wq[(size_t)b * G + i];
            lds.es.sm32[i] = (unsigned)(pbits[sidx[(size_t)b * G + i]] >> pbeg);
        }
        __syncthreads();

        const int lane = tid & 63;
        const int w = tid >> 6;
        // wave -> pathway slice within this block's 10: {0-2, 3-5, 6-7, 8-9}
        const int woff = (w == 0) ? 0 : (w == 1) ? 3 : (w == 2) ? 6 : 8;
        const int np   = (w < 2) ? 3 : 2;
        const int p0   = pbeg + woff;

        const int start = lane * LPW;
        const int cnt = (start + LPW < G) ? LPW : (G - start);

        // Pass A: per-chunk (sum w*hit, #hit) for np pathways at once
        double sw[3] = {0.0, 0.0, 0.0};
        int sh[3] = {0, 0, 0};
        for (int k = 0; k < cnt; ++k) {
            int s = start + k;
            unsigned nib = (lds.es.sm32[s] >> woff) & 7u;
            double wv = (double)lds.es.swq[s];
#pragma unroll
            for (int q = 0; q < 3; ++q) {
                if (q < np && ((nib >> q) & 1u)) { sw[q] += wv; sh[q]++; }
            }
        }
        double norm[3], inv_denom[3], running[3];
        int sht[3];
#pragma unroll
        for (int q = 0; q < 3; ++q) {
            double swt = sw[q];
            int shq = sh[q];
#pragma unroll
            for (int off = 1; off < 64; off <<= 1) {
                swt += __shfl_xor(swt, off, 64);
                shq += __shfl_xor(shq, off, 64);
            }
            sht[q] = shq;
            norm[q]      = (swt > 0.0) ? 1.0 / swt : 1.0;
            inv_denom[q] = 1.0 / fmax((double)(G - shq), 1.0);
            double csum = sw[q] * norm[q] - (double)(cnt - sh[q]) * inv_denom[q];
            double x = csum;
#pragma unroll
            for (int off = 1; off < 64; off <<= 1) {
                double vv = __shfl_up(x, off, 64);
                if (lane >= off) x += vv;
            }
            running[q] = x - csum;     // exclusive prefix for this chunk
        }

        // Pass C: walk chunk, first-occurrence argmax of |running|
        double bestv[3] = {-1.0, -1.0, -1.0};
        double bestr[3] = {0.0, 0.0, 0.0};
        int besti[3] = {0x7FFFFFFF, 0x7FFFFFFF, 0x7FFFFFFF};
        for (int k = 0; k < cnt; ++k) {
            int s = start + k;
            unsigned nib = (lds.es.sm32[s] >> woff) & 7u;
            double wv = (double)lds.es.swq[s];
#pragma unroll
            for (int q = 0; q < 3; ++q) {
                if (q < np) {
                    running[q] += ((nib >> q) & 1u) ? wv * norm[q] : -inv_denom[q];
                    double a = fabs(running[q]);
                    if (a > bestv[q]) { bestv[q] = a; bestr[q] = running[q]; besti[q] = s; }
                }
            }
        }
#pragma unroll
        for (int q = 0; q < 3; ++q) {
#pragma unroll
            for (int off = 1; off < 64; off <<= 1) {
                double ov  = __shfl_xor(bestv[q], off, 64);
                double orr = __shfl_xor(bestr[q], off, 64);
                int    oi  = __shfl_xor(besti[q], off, 64);
                if (ov > bestv[q] || (ov == bestv[q] && oi < besti[q])) {
                    bestv[q] = ov; bestr[q] = orr; besti[q] = oi;
                }
            }
        }

        if (lane == 0) {
#pragma unroll
            for (int q = 0; q < 3; ++q) {
                if (q < np) {
                    int p = p0 + q;
                    out[(size_t)b * P + p] = (sht[q] > 0) ? (float)bestr[q] : 0.0f;
                }
            }
        }
    }
}

extern "C" void kernel_launch(void* const* d_in, const int* in_sizes, int n_in,
                              void* d_out, int out_size, void* d_ws, size_t ws_size,
                              hipStream_t stream) {
    const float* expr    = (const float*)d_in[0];   // [B, G]
    const float* pathway = (const float*)d_in[1];   // [P, G]
    float* out = (float*)d_out;                     // [B, P]

    // workspace layout (bytes):
    //   pbits ull[G]        @ 0        (40960 reserved)
    //   runs  ull[B*NPAD]   @ 40960    (2621440)
    //   wq    f32[B*G]      @ 2662400  (1279744 -> next 3942144)
    //   sidx  u16[B*G]      @ 3942144  (639872)    total ~4.6 MB
    char* ws = (char*)d_ws;
    ull*            pbits = (ull*)ws;
    ull*            runs  = (ull*)(ws + 40960);
    float*          wqa   = (float*)(ws + 2662400);
    unsigned short* sidx  = (unsigned short*)(ws + 3942144);

    void* args[] = { (void*)&expr, (void*)&pathway, (void*)&pbits,
                     (void*)&runs, (void*)&wqa, (void*)&sidx, (void*)&out };
    hipLaunchCooperativeKernel((void*)fused_all, dim3(NRUN, Bc), dim3(256),
                               args, 0, stream);
}